// Round 1
// baseline (922.283 us; speedup 1.0000x reference)
//
#include <hip/hip_runtime.h>
#include <cstdint>
#include <cstddef>

typedef __bf16 bf16;
typedef __bf16 bf16x8 __attribute__((ext_vector_type(8)));
typedef float f32x4 __attribute__((ext_vector_type(4)));

__device__ __forceinline__ void gload_lds16(const bf16* g, bf16* l) {
    __builtin_amdgcn_global_load_lds((const __attribute__((address_space(1))) void*)g,
                                     (__attribute__((address_space(3))) void*)l, 16, 0, 0);
}

// ---------------- conversion kernels ----------------
__global__ void cvt_f32_bf16_kernel(const float* __restrict__ in, bf16* __restrict__ outp, size_t n) {
    const size_t i = ((size_t)blockIdx.x * 256 + threadIdx.x) * 8;
    if (i >= n) return;
    const float4 a = *(const float4*)(in + i);
    const float4 b = *(const float4*)(in + i + 4);
    bf16x8 o;
    o[0] = (bf16)a.x; o[1] = (bf16)a.y; o[2] = (bf16)a.z; o[3] = (bf16)a.w;
    o[4] = (bf16)b.x; o[5] = (bf16)b.y; o[6] = (bf16)b.z; o[7] = (bf16)b.w;
    *(bf16x8*)(outp + i) = o;
}

// Wt[n][k] = W[k][n]  (W is K x N)
__global__ void wtrans_kernel(const float* __restrict__ W, bf16* __restrict__ Wt, int K, int N) {
    const int idx = blockIdx.x * 256 + threadIdx.x;
    const int n = idx / K, k = idx - n * K;
    Wt[idx] = (bf16)W[(size_t)k * N + n];
}

// ---------------- GEMM: C[M][N] = A[M][K] @ Bt[N][K]^T + bias, optional exact GELU ----------------
// 128x128 tile, BK=64, 4 waves (each 64x64), global_load_lds staging, XOR-swizzled LDS.
__global__ void gemm_bf16_kernel(const bf16* __restrict__ A, const bf16* __restrict__ Bt,
                                 const float* __restrict__ bias, bf16* __restrict__ C,
                                 int K, int N, int do_gelu)
{
    __shared__ bf16 Alds[128 * 64];
    __shared__ bf16 Blds[128 * 64];
    const int t = threadIdx.x;
    const int w = t >> 6;
    const int l = t & 63;
    const int l15 = l & 15, l4 = l >> 4;
    const int m0 = blockIdx.y << 7;
    const int n0 = blockIdx.x << 7;
    const int wm = (w >> 1) << 6;
    const int wn = (w & 1) << 6;

    f32x4 acc[4][4] = {};

    int sr[4], sg[4];
#pragma unroll
    for (int i = 0; i < 4; ++i) {
        const int flat = i * 256 + t;
        sr[i] = flat >> 3;
        sg[i] = ((flat & 7) ^ (sr[i] & 7)) << 3;  // swizzled k-group offset (elements)
    }

    for (int k0 = 0; k0 < K; k0 += 64) {
#pragma unroll
        for (int i = 0; i < 4; ++i) {
            gload_lds16(A + (size_t)(m0 + sr[i]) * K + (k0 + sg[i]),
                        &Alds[(size_t)(i * 256 + (w << 6)) << 3]);
            gload_lds16(Bt + (size_t)(n0 + sr[i]) * K + (k0 + sg[i]),
                        &Blds[(size_t)(i * 256 + (w << 6)) << 3]);
        }
        __syncthreads();
#pragma unroll
        for (int kk = 0; kk < 2; ++kk) {
            bf16x8 af[4], bfv[4];
#pragma unroll
            for (int i = 0; i < 4; ++i) {
                const int r = wm + (i << 4) + l15;
                const int g = (kk << 2) + l4;
                af[i] = *(const bf16x8*)&Alds[(r << 6) + ((g ^ (r & 7)) << 3)];
                const int rn = wn + (i << 4) + l15;
                bfv[i] = *(const bf16x8*)&Blds[(rn << 6) + ((g ^ (rn & 7)) << 3)];
            }
#pragma unroll
            for (int i = 0; i < 4; ++i)
#pragma unroll
                for (int j = 0; j < 4; ++j)
                    acc[i][j] = __builtin_amdgcn_mfma_f32_16x16x32_bf16(af[i], bfv[j], acc[i][j], 0, 0, 0);
        }
        __syncthreads();
    }

#pragma unroll
    for (int i = 0; i < 4; ++i) {
        const int mb = m0 + wm + (i << 4) + (l4 << 2);
#pragma unroll
        for (int j = 0; j < 4; ++j) {
            const int col = n0 + wn + (j << 4) + l15;
            const float bv = bias[col];
#pragma unroll
            for (int r = 0; r < 4; ++r) {
                float v = acc[i][j][r] + bv;
                if (do_gelu) v = 0.5f * v * (1.0f + erff(v * 0.70710678118654752f));
                C[(size_t)(mb + r) * N + col] = (bf16)v;
            }
        }
    }
}

// ---------------- LayerNorm (in-place, one block of 128 per row) ----------------
template <int N>
__global__ void ln_kernel(bf16* __restrict__ H, const float* __restrict__ g,
                          const float* __restrict__ be)
{
    constexpr int NG = N / 8;
    const int t = threadIdx.x;
    bf16* hp = H + (size_t)blockIdx.x * N;
    float v[8];
    float s1 = 0.f, s2 = 0.f;
    if (t < NG) {
        const bf16x8 hv = *(const bf16x8*)(hp + t * 8);
#pragma unroll
        for (int e = 0; e < 8; ++e) { v[e] = (float)hv[e]; s1 += v[e]; s2 += v[e] * v[e]; }
    }
#pragma unroll
    for (int m = 1; m < 64; m <<= 1) { s1 += __shfl_xor(s1, m, 64); s2 += __shfl_xor(s2, m, 64); }
    __shared__ float red[4];
    const int w = t >> 6;
    if ((t & 63) == 0) { red[w] = s1; red[w + 2] = s2; }
    __syncthreads();
    s1 = red[0] + red[1];
    s2 = red[2] + red[3];
    const float mu = s1 * (1.0f / N);
    const float rstd = rsqrtf(s2 * (1.0f / N) - mu * mu + 1e-5f);
    if (t < NG) {
        const float4 g0 = *(const float4*)(g + t * 8);
        const float4 g1 = *(const float4*)(g + t * 8 + 4);
        const float4 b0 = *(const float4*)(be + t * 8);
        const float4 b1 = *(const float4*)(be + t * 8 + 4);
        bf16x8 o;
        o[0] = (bf16)((v[0] - mu) * rstd * g0.x + b0.x);
        o[1] = (bf16)((v[1] - mu) * rstd * g0.y + b0.y);
        o[2] = (bf16)((v[2] - mu) * rstd * g0.z + b0.z);
        o[3] = (bf16)((v[3] - mu) * rstd * g0.w + b0.w);
        o[4] = (bf16)((v[4] - mu) * rstd * g1.x + b1.x);
        o[5] = (bf16)((v[5] - mu) * rstd * g1.y + b1.y);
        o[6] = (bf16)((v[6] - mu) * rstd * g1.z + b1.z);
        o[7] = (bf16)((v[7] - mu) * rstd * g1.w + b1.w);
        *(bf16x8*)(hp + t * 8) = o;
    }
}

// ---------------- pooled mean (deterministic 2-pass) ----------------
__global__ void pool1_kernel(const bf16* __restrict__ Y, float* __restrict__ ppart) {
    const int c = blockIdx.x * 128 + threadIdx.x;   // 0..1151
    const int nc = blockIdx.y;                      // 0..35
    const int b = blockIdx.z;
    const bf16* yp = Y + ((size_t)b * 9216 + (size_t)nc * 256) * 1152 + c;
    float s = 0.f;
#pragma unroll 4
    for (int i = 0; i < 256; ++i) s += (float)yp[(size_t)i * 1152];
    ppart[((size_t)b * 36 + nc) * 1152 + c] = s;
}

__global__ void pool2_kernel(const float* __restrict__ ppart, float* __restrict__ pooled) {
    const int i = blockIdx.x * 256 + threadIdx.x;   // 0..9215
    const int b = i / 1152, c = i - b * 1152;
    float s = 0.f;
#pragma unroll
    for (int j = 0; j < 36; ++j) s += ppart[((size_t)b * 36 + j) * 1152 + c];
    pooled[i] = s;
}

// ---------------- SE MLP: s = sigmoid(relu(p@w1+b1)@w2+b2) ----------------
__global__ void se_kernel(const float* __restrict__ pooled,
                          const float* __restrict__ w1, const float* __restrict__ b1,
                          const float* __restrict__ w2, const float* __restrict__ b2,
                          float* __restrict__ sbuf)
{
    const int b = blockIdx.x, t = threadIdx.x;
    __shared__ float p[1152];
    __shared__ float t1[144];
    for (int c = t; c < 1152; c += 256) p[c] = pooled[b * 1152 + c] * (1.0f / 9216.0f);
    __syncthreads();
    if (t < 144) {
        float a = b1[t];
        for (int k = 0; k < 1152; ++k) a += p[k] * w1[k * 144 + t];
        t1[t] = a > 0.f ? a : 0.f;
    }
    __syncthreads();
    for (int c = t; c < 1152; c += 256) {
        float a = b2[c];
#pragma unroll 8
        for (int k = 0; k < 144; ++k) a += t1[k] * w2[k * 1152 + c];
        sbuf[b * 1152 + c] = 1.0f / (1.0f + expf(-a));
    }
}

// ---------------- windowed self-attention (one block per 32x32 window) ----------------
__global__ void attn_kernel(const bf16* __restrict__ Y, const float* __restrict__ sbuf,
                            float* __restrict__ out)
{
    __shared__ bf16 yw[32 * 384];     // y*s chunk, XOR-swizzled 16B groups
    __shared__ float Sp[4][32][33];   // per-wave score partials
    __shared__ bf16 P[32 * 32];       // softmax probs, row-major

    const int t = threadIdx.x;
    const int w = t >> 6, l = t & 63;
    const int l15 = l & 15, l4 = l >> 4;
    const int wdx = blockIdx.x, b = blockIdx.y;

    const bf16* Yp = Y + ((size_t)b * 9216 + (size_t)wdx * 32) * 1152;
    const float* sv = sbuf + b * 1152;
    float* op = out + ((size_t)b * 9216 + (size_t)wdx * 32) * 1152;

    auto stage_chunk = [&](int cc) {
#pragma unroll
        for (int i = 0; i < 6; ++i) {
            const int flat = i * 256 + t;      // 0..1535
            const int r = flat / 48;
            const int gg = flat - r * 48;
            const int c0 = cc * 384 + gg * 8;
            const bf16x8 yv = *(const bf16x8*)(Yp + (size_t)r * 1152 + c0);
            const float4 sa = *(const float4*)(sv + c0);
            const float4 sb = *(const float4*)(sv + c0 + 4);
            bf16x8 ov;
            ov[0] = (bf16)((float)yv[0] * sa.x);
            ov[1] = (bf16)((float)yv[1] * sa.y);
            ov[2] = (bf16)((float)yv[2] * sa.z);
            ov[3] = (bf16)((float)yv[3] * sa.w);
            ov[4] = (bf16)((float)yv[4] * sb.x);
            ov[5] = (bf16)((float)yv[5] * sb.y);
            ov[6] = (bf16)((float)yv[6] * sb.z);
            ov[7] = (bf16)((float)yv[7] * sb.w);
            *(bf16x8*)&yw[((r * 48) + (gg ^ (r & 7))) << 3] = ov;
        }
    };

    // ---- scores: S = Yw @ Yw^T (A-frag == B-frag for X@X^T) ----
    f32x4 acc[2][2] = {};
    for (int cc = 0; cc < 3; ++cc) {
        if (cc) __syncthreads();
        stage_chunk(cc);
        __syncthreads();
#pragma unroll
        for (int kkl = 0; kkl < 3; ++kkl) {
            const int g = ((w * 3 + kkl) << 2) + l4;   // group within chunk, 0..47
            bf16x8 af[2];
#pragma unroll
            for (int i = 0; i < 2; ++i) {
                const int r = (i << 4) + l15;
                af[i] = *(const bf16x8*)&yw[((r * 48) + (g ^ (r & 7))) << 3];
            }
#pragma unroll
            for (int i = 0; i < 2; ++i)
#pragma unroll
                for (int j = 0; j < 2; ++j)
                    acc[i][j] = __builtin_amdgcn_mfma_f32_16x16x32_bf16(af[i], af[j], acc[i][j], 0, 0, 0);
        }
    }
#pragma unroll
    for (int i = 0; i < 2; ++i)
#pragma unroll
        for (int j = 0; j < 2; ++j)
#pragma unroll
            for (int r = 0; r < 4; ++r)
                Sp[w][(i << 4) + (l4 << 2) + r][(j << 4) + l15] = acc[i][j][r];
    __syncthreads();

    // ---- softmax (f32): thread t handles row q=t>>3, 4 cols ----
    {
        const int q = t >> 3, u = t & 7;
        float v[4];
#pragma unroll
        for (int e = 0; e < 4; ++e) {
            const int k2 = (u << 2) + e;
            v[e] = (Sp[0][q][k2] + Sp[1][q][k2] + Sp[2][q][k2] + Sp[3][q][k2]) * 0.029462782549439483f;
        }
        float mx = fmaxf(fmaxf(v[0], v[1]), fmaxf(v[2], v[3]));
#pragma unroll
        for (int m = 1; m < 8; m <<= 1) mx = fmaxf(mx, __shfl_xor(mx, m, 64));
        float sm = 0.f;
#pragma unroll
        for (int e = 0; e < 4; ++e) { v[e] = expf(v[e] - mx); sm += v[e]; }
#pragma unroll
        for (int m = 1; m < 8; m <<= 1) sm += __shfl_xor(sm, m, 64);
        const float inv = 1.0f / sm;
#pragma unroll
        for (int e = 0; e < 4; ++e) P[(q << 5) + (u << 2) + e] = (bf16)(v[e] * inv);
    }
    __syncthreads();

    // ---- PV: out = P @ Yw; chunk order 2 (resident), 0, 1 ----
    bf16x8 pa[2];
#pragma unroll
    for (int i = 0; i < 2; ++i)
        pa[i] = *(const bf16x8*)&P[(((i << 4) + l15) << 5) + (l4 << 3)];

    for (int ci = 0; ci < 3; ++ci) {
        const int cc = (ci == 0) ? 2 : (ci - 1);
        if (ci) {
            __syncthreads();
            stage_chunk(cc);
            __syncthreads();
        }
        f32x4 pacc[2][6] = {};
#pragma unroll
        for (int jn = 0; jn < 6; ++jn) {
            const int nl = w * 96 + (jn << 4) + l15;    // col within chunk
            const int gg = nl >> 3, e = nl & 7;
            bf16x8 bv;
#pragma unroll
            for (int j = 0; j < 8; ++j) {
                const int kr = (l4 << 3) + j;           // window row = k index
                bv[j] = yw[(((kr * 48) + (gg ^ (kr & 7))) << 3) + e];
            }
#pragma unroll
            for (int i = 0; i < 2; ++i)
                pacc[i][jn] = __builtin_amdgcn_mfma_f32_16x16x32_bf16(pa[i], bv, pacc[i][jn], 0, 0, 0);
        }
#pragma unroll
        for (int i = 0; i < 2; ++i) {
            const int mb = (i << 4) + (l4 << 2);
#pragma unroll
            for (int jn = 0; jn < 6; ++jn) {
                const int cg = cc * 384 + w * 96 + (jn << 4) + l15;
#pragma unroll
                for (int r = 0; r < 4; ++r)
                    op[(size_t)(mb + r) * 1152 + cg] = pacc[i][jn][r];
            }
        }
    }
}

// ---------------- launcher ----------------
extern "C" void kernel_launch(void* const* d_in, const int* in_sizes, int n_in,
                              void* d_out, int out_size, void* d_ws, size_t ws_size,
                              hipStream_t stream)
{
    const float* x   = (const float*)d_in[0];
    const float* W1  = (const float*)d_in[1];
    const float* b1  = (const float*)d_in[2];
    const float* g1  = (const float*)d_in[3];
    const float* be1 = (const float*)d_in[4];
    const float* W2  = (const float*)d_in[5];
    const float* b2  = (const float*)d_in[6];
    const float* g2  = (const float*)d_in[7];
    const float* be2 = (const float*)d_in[8];
    const float* W3  = (const float*)d_in[9];
    const float* b3  = (const float*)d_in[10];
    const float* g3  = (const float*)d_in[11];
    const float* be3 = (const float*)d_in[12];
    const float* Wo  = (const float*)d_in[13];
    const float* bo  = (const float*)d_in[14];
    const float* cw1 = (const float*)d_in[15];
    const float* cb1 = (const float*)d_in[16];
    const float* cw2 = (const float*)d_in[17];
    const float* cb2 = (const float*)d_in[18];
    float* out = (float*)d_out;

    const int M = 8 * 9216;  // 73728 rows
    size_t off = 0;
    auto alloc = [&](size_t nbytes) {
        void* p = (char*)d_ws + off;
        off += (nbytes + 255) & ~(size_t)255;
        return p;
    };
    bf16* Xb  = (bf16*)alloc((size_t)M * 1152 * 2);  // x bf16; later reused as Y
    bf16* Hb  = (bf16*)alloc((size_t)M * 768 * 2);   // H1; later reused as H3
    bf16* H2  = (bf16*)alloc((size_t)M * 512 * 2);
    bf16* Wt1 = (bf16*)alloc(768ull * 1152 * 2);
    bf16* Wt2 = (bf16*)alloc(512ull * 768 * 2);
    bf16* Wt3 = (bf16*)alloc(256ull * 512 * 2);
    bf16* Wto = (bf16*)alloc(1152ull * 256 * 2);
    float* ppart  = (float*)alloc(8ull * 36 * 1152 * 4);
    float* pooled = (float*)alloc(8ull * 1152 * 4);
    float* sbuf   = (float*)alloc(8ull * 1152 * 4);
    bf16* H1 = Hb;
    bf16* H3 = Hb;
    bf16* Y  = Xb;

    cvt_f32_bf16_kernel<<<41472, 256, 0, stream>>>(x, Xb, (size_t)M * 1152);
    wtrans_kernel<<<3456, 256, 0, stream>>>(W1, Wt1, 1152, 768);
    wtrans_kernel<<<1536, 256, 0, stream>>>(W2, Wt2, 768, 512);
    wtrans_kernel<<<512,  256, 0, stream>>>(W3, Wt3, 512, 256);
    wtrans_kernel<<<1152, 256, 0, stream>>>(Wo, Wto, 256, 1152);

    gemm_bf16_kernel<<<dim3(6, 576), 256, 0, stream>>>(Xb, Wt1, b1, H1, 1152, 768, 1);
    ln_kernel<768><<<M, 128, 0, stream>>>(H1, g1, be1);
    gemm_bf16_kernel<<<dim3(4, 576), 256, 0, stream>>>(H1, Wt2, b2, H2, 768, 512, 1);
    ln_kernel<512><<<M, 128, 0, stream>>>(H2, g2, be2);
    gemm_bf16_kernel<<<dim3(2, 576), 256, 0, stream>>>(H2, Wt3, b3, H3, 512, 256, 1);
    ln_kernel<256><<<M, 128, 0, stream>>>(H3, g3, be3);
    gemm_bf16_kernel<<<dim3(9, 576), 256, 0, stream>>>(H3, Wto, bo, Y, 256, 1152, 0);

    pool1_kernel<<<dim3(9, 36, 8), 128, 0, stream>>>(Y, ppart);
    pool2_kernel<<<36, 256, 0, stream>>>(ppart, pooled);
    se_kernel<<<8, 256, 0, stream>>>(pooled, cw1, cb1, cw2, cb2, sbuf);
    attn_kernel<<<dim3(288, 8), 256, 0, stream>>>(Y, sbuf, out);
}

// Round 2
// 869.663 us; speedup vs baseline: 1.0605x; 1.0605x over previous
//
#include <hip/hip_runtime.h>
#include <cstdint>
#include <cstddef>

typedef __bf16 bf16;
typedef __bf16 bf16x8 __attribute__((ext_vector_type(8)));
typedef float f32x4 __attribute__((ext_vector_type(4)));

__device__ __forceinline__ void gload_lds16(const bf16* g, bf16* l) {
    __builtin_amdgcn_global_load_lds((const __attribute__((address_space(1))) void*)g,
                                     (__attribute__((address_space(3))) void*)l, 16, 0, 0);
}
__device__ __forceinline__ void gload_lds16f(const float* g, float* l) {
    __builtin_amdgcn_global_load_lds((const __attribute__((address_space(1))) void*)g,
                                     (__attribute__((address_space(3))) void*)l, 16, 0, 0);
}

// Wt[n][k] = W[k][n]  (W is K x N)
__global__ void wtrans_kernel(const float* __restrict__ W, bf16* __restrict__ Wt, int K, int N) {
    const int idx = blockIdx.x * 256 + threadIdx.x;
    const int n = idx / K, k = idx - n * K;
    Wt[idx] = (bf16)W[(size_t)k * N + n];
}

// XCD-aware bijective swizzle: bid -> wgid (requires nwg % 8 == 0)
__device__ __forceinline__ int xcd_swz(int bid, int nwg) {
    return (bid & 7) * (nwg >> 3) + (bid >> 3);
}

// ---------------- GEMM (bf16 A): C[M][N] = A @ Bt^T + bias, optional exact GELU ----------------
__global__ void gemm_bf16_kernel(const bf16* __restrict__ A, const bf16* __restrict__ Bt,
                                 const float* __restrict__ bias, bf16* __restrict__ C,
                                 int K, int N, int nx, int do_gelu)
{
    __shared__ bf16 Alds[128 * 64];
    __shared__ bf16 Blds[128 * 64];
    const int t = threadIdx.x;
    const int w = t >> 6;
    const int l = t & 63;
    const int l15 = l & 15, l4 = l >> 4;
    const int wgid = xcd_swz(blockIdx.x, gridDim.x);
    const int mblk = wgid / nx;
    const int nblk = wgid - mblk * nx;
    const int m0 = mblk << 7;
    const int n0 = nblk << 7;
    const int wm = (w >> 1) << 6;
    const int wn = (w & 1) << 6;

    f32x4 acc[4][4] = {};

    int sr[4], sg[4];
#pragma unroll
    for (int i = 0; i < 4; ++i) {
        const int flat = i * 256 + t;
        sr[i] = flat >> 3;
        sg[i] = ((flat & 7) ^ (sr[i] & 7)) << 3;
    }

    for (int k0 = 0; k0 < K; k0 += 64) {
#pragma unroll
        for (int i = 0; i < 4; ++i) {
            gload_lds16(A + (size_t)(m0 + sr[i]) * K + (k0 + sg[i]),
                        &Alds[(size_t)(i * 256 + (w << 6)) << 3]);
            gload_lds16(Bt + (size_t)(n0 + sr[i]) * K + (k0 + sg[i]),
                        &Blds[(size_t)(i * 256 + (w << 6)) << 3]);
        }
        __syncthreads();
#pragma unroll
        for (int kk = 0; kk < 2; ++kk) {
            bf16x8 af[4], bfv[4];
#pragma unroll
            for (int i = 0; i < 4; ++i) {
                const int r = wm + (i << 4) + l15;
                const int g = (kk << 2) + l4;
                af[i] = *(const bf16x8*)&Alds[(r << 6) + ((g ^ (r & 7)) << 3)];
                const int rn = wn + (i << 4) + l15;
                bfv[i] = *(const bf16x8*)&Blds[(rn << 6) + ((g ^ (rn & 7)) << 3)];
            }
#pragma unroll
            for (int i = 0; i < 4; ++i)
#pragma unroll
                for (int j = 0; j < 4; ++j)
                    acc[i][j] = __builtin_amdgcn_mfma_f32_16x16x32_bf16(af[i], bfv[j], acc[i][j], 0, 0, 0);
        }
        __syncthreads();
    }

#pragma unroll
    for (int i = 0; i < 4; ++i) {
        const int mb = m0 + wm + (i << 4) + (l4 << 2);
#pragma unroll
        for (int j = 0; j < 4; ++j) {
            const int col = n0 + wn + (j << 4) + l15;
            const float bv = bias[col];
#pragma unroll
            for (int r = 0; r < 4; ++r) {
                float v = acc[i][j][r] + bv;
                if (do_gelu) v = 0.5f * v * (1.0f + erff(v * 0.70710678118654752f));
                C[(size_t)(mb + r) * N + col] = (bf16)v;
            }
        }
    }
}

// ---------------- GEMM1 (f32 A, fused cvt + GELU): C = gelu(A @ Bt^T + bias) ----------------
__global__ void gemm_f32a_kernel(const float* __restrict__ A, const bf16* __restrict__ Bt,
                                 const float* __restrict__ bias, bf16* __restrict__ C,
                                 int K, int N, int nx)
{
    __shared__ float Af32[128 * 64];
    __shared__ bf16  Blds[128 * 64];
    const int t = threadIdx.x;
    const int w = t >> 6;
    const int l = t & 63;
    const int l15 = l & 15, l4 = l >> 4;
    const int wgid = xcd_swz(blockIdx.x, gridDim.x);
    const int mblk = wgid / nx;
    const int nblk = wgid - mblk * nx;
    const int m0 = mblk << 7;
    const int n0 = nblk << 7;
    const int wm = (w >> 1) << 6;
    const int wn = (w & 1) << 6;

    f32x4 acc[4][4] = {};

    // A staging map: 8 iters x 256 threads, 16B = 4 floats per lane
    int ar[8], ag[8];
#pragma unroll
    for (int i = 0; i < 8; ++i) {
        const int flat = i * 256 + t;          // 0..2047
        ar[i] = flat >> 4;                     // row 0..127
        ag[i] = ((flat & 15) ^ (ar[i] & 7)) << 2;  // swizzled float offset
    }
    int br[4], bg[4];
#pragma unroll
    for (int i = 0; i < 4; ++i) {
        const int flat = i * 256 + t;
        br[i] = flat >> 3;
        bg[i] = ((flat & 7) ^ (br[i] & 7)) << 3;
    }

    for (int k0 = 0; k0 < K; k0 += 64) {
#pragma unroll
        for (int i = 0; i < 8; ++i)
            gload_lds16f(A + (size_t)(m0 + ar[i]) * K + (k0 + ag[i]),
                         &Af32[(size_t)(i * 256 + (w << 6)) << 2]);
#pragma unroll
        for (int i = 0; i < 4; ++i)
            gload_lds16(Bt + (size_t)(n0 + br[i]) * K + (k0 + bg[i]),
                        &Blds[(size_t)(i * 256 + (w << 6)) << 3]);
        __syncthreads();
#pragma unroll
        for (int kk = 0; kk < 2; ++kk) {
            bf16x8 af[4], bfv[4];
#pragma unroll
            for (int i = 0; i < 4; ++i) {
                const int r = wm + (i << 4) + l15;
                const int fg = (kk << 3) + (l4 << 1);      // f32 16B-group base, 0..15
                const float4 fa = *(const float4*)&Af32[(r << 6) + ((fg ^ (r & 7)) << 2)];
                const float4 fb = *(const float4*)&Af32[(r << 6) + (((fg + 1) ^ (r & 7)) << 2)];
                bf16x8 a;
                a[0] = (bf16)fa.x; a[1] = (bf16)fa.y; a[2] = (bf16)fa.z; a[3] = (bf16)fa.w;
                a[4] = (bf16)fb.x; a[5] = (bf16)fb.y; a[6] = (bf16)fb.z; a[7] = (bf16)fb.w;
                af[i] = a;
                const int rn = wn + (i << 4) + l15;
                const int g = (kk << 2) + l4;
                bfv[i] = *(const bf16x8*)&Blds[(rn << 6) + ((g ^ (rn & 7)) << 3)];
            }
#pragma unroll
            for (int i = 0; i < 4; ++i)
#pragma unroll
                for (int j = 0; j < 4; ++j)
                    acc[i][j] = __builtin_amdgcn_mfma_f32_16x16x32_bf16(af[i], bfv[j], acc[i][j], 0, 0, 0);
        }
        __syncthreads();
    }

#pragma unroll
    for (int i = 0; i < 4; ++i) {
        const int mb = m0 + wm + (i << 4) + (l4 << 2);
#pragma unroll
        for (int j = 0; j < 4; ++j) {
            const int col = n0 + wn + (j << 4) + l15;
            const float bv = bias[col];
#pragma unroll
            for (int r = 0; r < 4; ++r) {
                float v = acc[i][j][r] + bv;
                v = 0.5f * v * (1.0f + erff(v * 0.70710678118654752f));
                C[(size_t)(mb + r) * N + col] = (bf16)v;
            }
        }
    }
}

// ---------------- LayerNorms ----------------
// N=768: 2 rows per 256-thread block (128 threads/row, 96 active)
__global__ void ln768_kernel(bf16* __restrict__ H, const float* __restrict__ g,
                             const float* __restrict__ be)
{
    const int t = threadIdx.x;
    const int rloc = t >> 7;
    const int u = t & 127;
    bf16* hp = H + ((size_t)blockIdx.x * 2 + rloc) * 768;
    float v[8];
    float s1 = 0.f, s2 = 0.f;
    if (u < 96) {
        const bf16x8 hv = *(const bf16x8*)(hp + u * 8);
#pragma unroll
        for (int e = 0; e < 8; ++e) { v[e] = (float)hv[e]; s1 += v[e]; s2 += v[e] * v[e]; }
    }
#pragma unroll
    for (int m = 1; m < 64; m <<= 1) { s1 += __shfl_xor(s1, m, 64); s2 += __shfl_xor(s2, m, 64); }
    __shared__ float red[8];
    const int w = t >> 6;
    if ((t & 63) == 0) { red[w] = s1; red[w + 4] = s2; }
    __syncthreads();
    const int wb = rloc << 1;
    s1 = red[wb] + red[wb + 1];
    s2 = red[wb + 4] + red[wb + 5];
    const float mu = s1 * (1.0f / 768.0f);
    const float rstd = rsqrtf(s2 * (1.0f / 768.0f) - mu * mu + 1e-5f);
    if (u < 96) {
        const float4 g0 = *(const float4*)(g + u * 8);
        const float4 g1 = *(const float4*)(g + u * 8 + 4);
        const float4 b0 = *(const float4*)(be + u * 8);
        const float4 b1 = *(const float4*)(be + u * 8 + 4);
        bf16x8 o;
        o[0] = (bf16)((v[0] - mu) * rstd * g0.x + b0.x);
        o[1] = (bf16)((v[1] - mu) * rstd * g0.y + b0.y);
        o[2] = (bf16)((v[2] - mu) * rstd * g0.z + b0.z);
        o[3] = (bf16)((v[3] - mu) * rstd * g0.w + b0.w);
        o[4] = (bf16)((v[4] - mu) * rstd * g1.x + b1.x);
        o[5] = (bf16)((v[5] - mu) * rstd * g1.y + b1.y);
        o[6] = (bf16)((v[6] - mu) * rstd * g1.z + b1.z);
        o[7] = (bf16)((v[7] - mu) * rstd * g1.w + b1.w);
        *(bf16x8*)(hp + u * 8) = o;
    }
}

// N=512: one wave per row, 4 rows per 256-thread block
__global__ void ln512_kernel(bf16* __restrict__ H, const float* __restrict__ g,
                             const float* __restrict__ be)
{
    const int t = threadIdx.x;
    const int w = t >> 6, l = t & 63;
    bf16* hp = H + ((size_t)blockIdx.x * 4 + w) * 512;
    const bf16x8 hv = *(const bf16x8*)(hp + l * 8);
    float v[8];
    float s1 = 0.f, s2 = 0.f;
#pragma unroll
    for (int e = 0; e < 8; ++e) { v[e] = (float)hv[e]; s1 += v[e]; s2 += v[e] * v[e]; }
#pragma unroll
    for (int m = 1; m < 64; m <<= 1) { s1 += __shfl_xor(s1, m, 64); s2 += __shfl_xor(s2, m, 64); }
    const float mu = s1 * (1.0f / 512.0f);
    const float rstd = rsqrtf(s2 * (1.0f / 512.0f) - mu * mu + 1e-5f);
    const float4 g0 = *(const float4*)(g + l * 8);
    const float4 g1 = *(const float4*)(g + l * 8 + 4);
    const float4 b0 = *(const float4*)(be + l * 8);
    const float4 b1 = *(const float4*)(be + l * 8 + 4);
    bf16x8 o;
    o[0] = (bf16)((v[0] - mu) * rstd * g0.x + b0.x);
    o[1] = (bf16)((v[1] - mu) * rstd * g0.y + b0.y);
    o[2] = (bf16)((v[2] - mu) * rstd * g0.z + b0.z);
    o[3] = (bf16)((v[3] - mu) * rstd * g0.w + b0.w);
    o[4] = (bf16)((v[4] - mu) * rstd * g1.x + b1.x);
    o[5] = (bf16)((v[5] - mu) * rstd * g1.y + b1.y);
    o[6] = (bf16)((v[6] - mu) * rstd * g1.z + b1.z);
    o[7] = (bf16)((v[7] - mu) * rstd * g1.w + b1.w);
    *(bf16x8*)(hp + l * 8) = o;
}

// N=256: half-wave (32 lanes) per row, 8 rows per 256-thread block
__global__ void ln256_kernel(bf16* __restrict__ H, const float* __restrict__ g,
                             const float* __restrict__ be)
{
    const int t = threadIdx.x;
    const int rloc = t >> 5, l = t & 31;
    bf16* hp = H + ((size_t)blockIdx.x * 8 + rloc) * 256;
    const bf16x8 hv = *(const bf16x8*)(hp + l * 8);
    float v[8];
    float s1 = 0.f, s2 = 0.f;
#pragma unroll
    for (int e = 0; e < 8; ++e) { v[e] = (float)hv[e]; s1 += v[e]; s2 += v[e] * v[e]; }
#pragma unroll
    for (int m = 1; m < 32; m <<= 1) { s1 += __shfl_xor(s1, m, 64); s2 += __shfl_xor(s2, m, 64); }
    const float mu = s1 * (1.0f / 256.0f);
    const float rstd = rsqrtf(s2 * (1.0f / 256.0f) - mu * mu + 1e-5f);
    const float4 g0 = *(const float4*)(g + l * 8);
    const float4 g1 = *(const float4*)(g + l * 8 + 4);
    const float4 b0 = *(const float4*)(be + l * 8);
    const float4 b1 = *(const float4*)(be + l * 8 + 4);
    bf16x8 o;
    o[0] = (bf16)((v[0] - mu) * rstd * g0.x + b0.x);
    o[1] = (bf16)((v[1] - mu) * rstd * g0.y + b0.y);
    o[2] = (bf16)((v[2] - mu) * rstd * g0.z + b0.z);
    o[3] = (bf16)((v[3] - mu) * rstd * g0.w + b0.w);
    o[4] = (bf16)((v[4] - mu) * rstd * g1.x + b1.x);
    o[5] = (bf16)((v[5] - mu) * rstd * g1.y + b1.y);
    o[6] = (bf16)((v[6] - mu) * rstd * g1.z + b1.z);
    o[7] = (bf16)((v[7] - mu) * rstd * g1.w + b1.w);
    *(bf16x8*)(hp + l * 8) = o;
}

// ---------------- pooled mean (deterministic 2-pass) ----------------
__global__ void pool1_kernel(const bf16* __restrict__ Y, float* __restrict__ ppart) {
    const int c = blockIdx.x * 128 + threadIdx.x;
    const int nc = blockIdx.y;
    const int b = blockIdx.z;
    const bf16* yp = Y + ((size_t)b * 9216 + (size_t)nc * 256) * 1152 + c;
    float s = 0.f;
#pragma unroll 4
    for (int i = 0; i < 256; ++i) s += (float)yp[(size_t)i * 1152];
    ppart[((size_t)b * 36 + nc) * 1152 + c] = s;
}

__global__ void pool2_kernel(const float* __restrict__ ppart, float* __restrict__ pooled) {
    const int i = blockIdx.x * 256 + threadIdx.x;
    const int b = i / 1152, c = i - b * 1152;
    float s = 0.f;
#pragma unroll
    for (int j = 0; j < 36; ++j) s += ppart[((size_t)b * 36 + j) * 1152 + c];
    pooled[i] = s;
}

// ---------------- SE MLP ----------------
__global__ void se_kernel(const float* __restrict__ pooled,
                          const float* __restrict__ w1, const float* __restrict__ b1,
                          const float* __restrict__ w2, const float* __restrict__ b2,
                          float* __restrict__ sbuf)
{
    const int b = blockIdx.x, t = threadIdx.x;
    __shared__ float p[1152];
    __shared__ float t1[144];
    for (int c = t; c < 1152; c += 256) p[c] = pooled[b * 1152 + c] * (1.0f / 9216.0f);
    __syncthreads();
    if (t < 144) {
        float a = b1[t];
        for (int k = 0; k < 1152; ++k) a += p[k] * w1[k * 144 + t];
        t1[t] = a > 0.f ? a : 0.f;
    }
    __syncthreads();
    for (int c = t; c < 1152; c += 256) {
        float a = b2[c];
#pragma unroll 8
        for (int k = 0; k < 144; ++k) a += t1[k] * w2[k * 1152 + c];
        sbuf[b * 1152 + c] = 1.0f / (1.0f + expf(-a));
    }
}

// ---------------- windowed self-attention ----------------
__global__ void attn_kernel(const bf16* __restrict__ Y, const float* __restrict__ sbuf,
                            float* __restrict__ out)
{
    __shared__ bf16 yw[32 * 384];
    __shared__ float Sp[4][32][33];
    __shared__ bf16 P[32 * 32];

    const int t = threadIdx.x;
    const int w = t >> 6, l = t & 63;
    const int l15 = l & 15, l4 = l >> 4;
    const int wdx = blockIdx.x, b = blockIdx.y;

    const bf16* Yp = Y + ((size_t)b * 9216 + (size_t)wdx * 32) * 1152;
    const float* sv = sbuf + b * 1152;
    float* op = out + ((size_t)b * 9216 + (size_t)wdx * 32) * 1152;

    auto stage_chunk = [&](int cc) {
#pragma unroll
        for (int i = 0; i < 6; ++i) {
            const int flat = i * 256 + t;
            const int r = flat / 48;
            const int gg = flat - r * 48;
            const int c0 = cc * 384 + gg * 8;
            const bf16x8 yv = *(const bf16x8*)(Yp + (size_t)r * 1152 + c0);
            const float4 sa = *(const float4*)(sv + c0);
            const float4 sb = *(const float4*)(sv + c0 + 4);
            bf16x8 ov;
            ov[0] = (bf16)((float)yv[0] * sa.x);
            ov[1] = (bf16)((float)yv[1] * sa.y);
            ov[2] = (bf16)((float)yv[2] * sa.z);
            ov[3] = (bf16)((float)yv[3] * sa.w);
            ov[4] = (bf16)((float)yv[4] * sb.x);
            ov[5] = (bf16)((float)yv[5] * sb.y);
            ov[6] = (bf16)((float)yv[6] * sb.z);
            ov[7] = (bf16)((float)yv[7] * sb.w);
            *(bf16x8*)&yw[((r * 48) + (gg ^ (r & 7))) << 3] = ov;
        }
    };

    f32x4 acc[2][2] = {};
    for (int cc = 0; cc < 3; ++cc) {
        if (cc) __syncthreads();
        stage_chunk(cc);
        __syncthreads();
#pragma unroll
        for (int kkl = 0; kkl < 3; ++kkl) {
            const int g = ((w * 3 + kkl) << 2) + l4;
            bf16x8 af[2];
#pragma unroll
            for (int i = 0; i < 2; ++i) {
                const int r = (i << 4) + l15;
                af[i] = *(const bf16x8*)&yw[((r * 48) + (g ^ (r & 7))) << 3];
            }
#pragma unroll
            for (int i = 0; i < 2; ++i)
#pragma unroll
                for (int j = 0; j < 2; ++j)
                    acc[i][j] = __builtin_amdgcn_mfma_f32_16x16x32_bf16(af[i], af[j], acc[i][j], 0, 0, 0);
        }
    }
#pragma unroll
    for (int i = 0; i < 2; ++i)
#pragma unroll
        for (int j = 0; j < 2; ++j)
#pragma unroll
            for (int r = 0; r < 4; ++r)
                Sp[w][(i << 4) + (l4 << 2) + r][(j << 4) + l15] = acc[i][j][r];
    __syncthreads();

    {
        const int q = t >> 3, u = t & 7;
        float v[4];
#pragma unroll
        for (int e = 0; e < 4; ++e) {
            const int k2 = (u << 2) + e;
            v[e] = (Sp[0][q][k2] + Sp[1][q][k2] + Sp[2][q][k2] + Sp[3][q][k2]) * 0.029462782549439483f;
        }
        float mx = fmaxf(fmaxf(v[0], v[1]), fmaxf(v[2], v[3]));
#pragma unroll
        for (int m = 1; m < 8; m <<= 1) mx = fmaxf(mx, __shfl_xor(mx, m, 64));
        float sm = 0.f;
#pragma unroll
        for (int e = 0; e < 4; ++e) { v[e] = expf(v[e] - mx); sm += v[e]; }
#pragma unroll
        for (int m = 1; m < 8; m <<= 1) sm += __shfl_xor(sm, m, 64);
        const float inv = 1.0f / sm;
#pragma unroll
        for (int e = 0; e < 4; ++e) P[(q << 5) + (u << 2) + e] = (bf16)(v[e] * inv);
    }
    __syncthreads();

    bf16x8 pa[2];
#pragma unroll
    for (int i = 0; i < 2; ++i)
        pa[i] = *(const bf16x8*)&P[(((i << 4) + l15) << 5) + (l4 << 3)];

    for (int ci = 0; ci < 3; ++ci) {
        const int cc = (ci == 0) ? 2 : (ci - 1);
        if (ci) {
            __syncthreads();
            stage_chunk(cc);
            __syncthreads();
        }
        f32x4 pacc[2][6] = {};
#pragma unroll
        for (int jn = 0; jn < 6; ++jn) {
            const int nl = w * 96 + (jn << 4) + l15;
            const int gg = nl >> 3, e = nl & 7;
            bf16x8 bv;
#pragma unroll
            for (int j = 0; j < 8; ++j) {
                const int kr = (l4 << 3) + j;
                bv[j] = yw[(((kr * 48) + (gg ^ (kr & 7))) << 3) + e];
            }
#pragma unroll
            for (int i = 0; i < 2; ++i)
                pacc[i][jn] = __builtin_amdgcn_mfma_f32_16x16x32_bf16(pa[i], bv, pacc[i][jn], 0, 0, 0);
        }
#pragma unroll
        for (int i = 0; i < 2; ++i) {
            const int mb = (i << 4) + (l4 << 2);
#pragma unroll
            for (int jn = 0; jn < 6; ++jn) {
                const int cg = cc * 384 + w * 96 + (jn << 4) + l15;
#pragma unroll
                for (int r = 0; r < 4; ++r)
                    op[(size_t)(mb + r) * 1152 + cg] = pacc[i][jn][r];
            }
        }
    }
}

// ---------------- launcher ----------------
extern "C" void kernel_launch(void* const* d_in, const int* in_sizes, int n_in,
                              void* d_out, int out_size, void* d_ws, size_t ws_size,
                              hipStream_t stream)
{
    const float* x   = (const float*)d_in[0];
    const float* W1  = (const float*)d_in[1];
    const float* b1  = (const float*)d_in[2];
    const float* g1  = (const float*)d_in[3];
    const float* be1 = (const float*)d_in[4];
    const float* W2  = (const float*)d_in[5];
    const float* b2  = (const float*)d_in[6];
    const float* g2  = (const float*)d_in[7];
    const float* be2 = (const float*)d_in[8];
    const float* W3  = (const float*)d_in[9];
    const float* b3  = (const float*)d_in[10];
    const float* g3  = (const float*)d_in[11];
    const float* be3 = (const float*)d_in[12];
    const float* Wo  = (const float*)d_in[13];
    const float* bo  = (const float*)d_in[14];
    const float* cw1 = (const float*)d_in[15];
    const float* cb1 = (const float*)d_in[16];
    const float* cw2 = (const float*)d_in[17];
    const float* cb2 = (const float*)d_in[18];
    float* out = (float*)d_out;

    const int M = 8 * 9216;  // 73728 rows
    size_t off = 0;
    auto alloc = [&](size_t nbytes) {
        void* p = (char*)d_ws + off;
        off += (nbytes + 255) & ~(size_t)255;
        return p;
    };
    bf16* Yb  = (bf16*)alloc((size_t)M * 1152 * 2);  // final y (bf16)
    bf16* Hb  = (bf16*)alloc((size_t)M * 768 * 2);   // H1; later reused as H3
    bf16* H2  = (bf16*)alloc((size_t)M * 512 * 2);
    bf16* Wt1 = (bf16*)alloc(768ull * 1152 * 2);
    bf16* Wt2 = (bf16*)alloc(512ull * 768 * 2);
    bf16* Wt3 = (bf16*)alloc(256ull * 512 * 2);
    bf16* Wto = (bf16*)alloc(1152ull * 256 * 2);
    float* ppart  = (float*)alloc(8ull * 36 * 1152 * 4);
    float* pooled = (float*)alloc(8ull * 1152 * 4);
    float* sbuf   = (float*)alloc(8ull * 1152 * 4);
    bf16* H1 = Hb;
    bf16* H3 = Hb;

    wtrans_kernel<<<3456, 256, 0, stream>>>(W1, Wt1, 1152, 768);
    wtrans_kernel<<<1536, 256, 0, stream>>>(W2, Wt2, 768, 512);
    wtrans_kernel<<<512,  256, 0, stream>>>(W3, Wt3, 512, 256);
    wtrans_kernel<<<1152, 256, 0, stream>>>(Wo, Wto, 256, 1152);

    gemm_f32a_kernel<<<6 * 576, 256, 0, stream>>>(x, Wt1, b1, H1, 1152, 768, 6);
    ln768_kernel<<<M / 2, 256, 0, stream>>>(H1, g1, be1);
    gemm_bf16_kernel<<<4 * 576, 256, 0, stream>>>(H1, Wt2, b2, H2, 768, 512, 4, 1);
    ln512_kernel<<<M / 4, 256, 0, stream>>>(H2, g2, be2);
    gemm_bf16_kernel<<<2 * 576, 256, 0, stream>>>(H2, Wt3, b3, H3, 512, 256, 2, 1);
    ln256_kernel<<<M / 8, 256, 0, stream>>>(H3, g3, be3);
    gemm_bf16_kernel<<<9 * 576, 256, 0, stream>>>(H3, Wto, bo, Yb, 256, 1152, 9, 0);

    pool1_kernel<<<dim3(9, 36, 8), 128, 0, stream>>>(Yb, ppart);
    pool2_kernel<<<36, 256, 0, stream>>>(ppart, pooled);
    se_kernel<<<8, 256, 0, stream>>>(pooled, cw1, cb1, cw2, cb2, sbuf);
    attn_kernel<<<dim3(288, 8), 256, 0, stream>>>(Yb, sbuf, out);
}